// Round 11
// baseline (159.279 us; speedup 1.0000x reference)
//
#include <hip/hip_runtime.h>

#define NATOMS 13
#define NP (NATOMS * NATOMS)   // 169

constexpr int N_ = 1024;   // rows
constexpr int H_ = 512;    // inner dim
constexpr int O_ = 512;    // output dim
constexpr int RB = 4;      // rows per W stream (quad)
constexpr int OSPLIT = 2;
constexpr int OC = O_ / OSPLIT;        // 256 cols per panel (1KB contiguous)
constexpr int MAXQUAD = 384;           // >= sum ceil(c_g/4) (<=382)
constexpr int NB = MAXQUAD * OSPLIT;   // 768 blocks (div by 8)
constexpr int RECS = 8;    // ints per quad record: rows[4], id, pad

// ws ints: [0] nquads; records at ws+16: [quad*RECS + {0..3}] rows, [+4] id
// ----------------------------------------------------------------- build quads
__global__ void build_quads(const int* __restrict__ x,
                            const int* __restrict__ fact,
                            int* __restrict__ ws, int N) {
    __shared__ int s_id[N_];
    __shared__ int s_cnt[NP];
    __shared__ int s_start[NP];
    __shared__ int s_qstart[NP];
    __shared__ int s_pos[NP];
    __shared__ int s_sorted[N_];
    const int tid = threadIdx.x, bd = blockDim.x;

    for (int i = tid; i < NP; i += bd) { s_cnt[i] = 0; s_pos[i] = 0; }
    __syncthreads();
    for (int n = tid; n < N; n += bd) {
        const int f0 = fact[2 * n];
        const int id = x[f0 * 3 + 1] * NATOMS + x[f0 * 3 + 2];
        s_id[n] = id;
        atomicAdd(&s_cnt[id], 1);
    }
    __syncthreads();
    if (tid == 0) {
        int run = 0, qrun = 0;
        for (int g = 0; g < NP; ++g) {
            s_start[g] = run;   run  += s_cnt[g];
            s_qstart[g] = qrun; qrun += (s_cnt[g] + RB - 1) / RB;
        }
        ws[0] = qrun;  // nquads
    }
    __syncthreads();
    for (int n = tid; n < N; n += bd) {
        const int id = s_id[n];
        const int p = atomicAdd(&s_pos[id], 1);
        s_sorted[s_start[id] + p] = n;
    }
    __syncthreads();
    for (int g = tid; g < NP; g += bd) {
        const int c = s_cnt[g], st = s_start[g], qs = s_qstart[g];
        const int nq = (c + RB - 1) / RB;
        for (int k = 0; k < nq; ++k) {
            int* rec = ws + 16 + (size_t)(qs + k) * RECS;
            for (int r = 0; r < RB; ++r) {
                const int idx = k * RB + r;
                rec[r] = (idx < c) ? s_sorted[st + idx] : -1;
            }
            rec[RB] = g;
        }
    }
}

// ------------------------------------------------------------------ quad GEMV
// Identical to R10. Idempotent (direct stores, no atomics) -> safe to launch
// multiple times; round 11 launches it 4x as a timing-decomposition probe.
__global__ __launch_bounds__(256)
void quad_gemv(const int* __restrict__ ws,
               const float* __restrict__ inp,
               const float* __restrict__ params,
               const float* __restrict__ bias,
               const int* __restrict__ msg_to_p,
               const int* __restrict__ order_p,
               float* __restrict__ out, int N) {
    constexpr int q = NB / 8;
    const int b = blockIdx.x;
    const int Lg = (b & 7) * q + (b >> 3);
    const int quad = Lg >> 1;
    const int op   = Lg & 1;

    if (quad >= ws[0]) return;
    const int* rec = ws + 16 + (size_t)quad * RECS;
    const int id = rec[RB];

    const int msg_to = *msg_to_p;
    const int order  = *order_p;
    const int tid = threadIdx.x;
    const int sub = tid >> 6;        // 0..3: h-phase
    const int l   = tid & 63;        // col-quad within 256-col panel
    const int o0  = op * OC;

    __shared__ float  fp_s[H_][RB];      // 8 KB, [h][r]
    __shared__ float4 red[4][RB][64];    // 16 KB, [sub][r][l]

#pragma unroll
    for (int r = 0; r < RB; ++r) {
        const int row = rec[r];
        if (row >= 0) {
#pragma unroll
            for (int k = 0; k < H_ / 256; ++k) {
                const int h = k * 256 + tid;
                float p = 1.0f;
                for (int i = 0; i < order; ++i)
                    if (i != msg_to)
                        p *= inp[((size_t)i * N + row) * H_ + h];
                fp_s[h][r] = p;
            }
        } else {
#pragma unroll
            for (int k = 0; k < H_ / 256; ++k) fp_s[k * 256 + tid][r] = 0.0f;
        }
    }
    __syncthreads();

    const float* __restrict__ wbase =
        params + (size_t)id * H_ * O_ + (size_t)sub * O_ + o0 + 4 * l;

    float4 a0 = make_float4(0,0,0,0), a1 = a0, a2 = a0, a3 = a0;

#define FMA4(acc, s, wv) acc.x += (s) * wv.x; acc.y += (s) * wv.y;    \
                         acc.z += (s) * wv.z; acc.w += (s) * wv.w;
#pragma unroll 8
    for (int hh = 0; hh < H_ / 4; ++hh) {
        const float4 w = *(const float4*)(wbase + (size_t)hh * 4 * O_);
        const float4 f = *(const float4*)&fp_s[4 * hh + sub][0];
        FMA4(a0, f.x, w)
        FMA4(a1, f.y, w)
        FMA4(a2, f.z, w)
        FMA4(a3, f.w, w)
    }
#undef FMA4

    red[sub][0][l] = a0;
    red[sub][1][l] = a1;
    red[sub][2][l] = a2;
    red[sub][3][l] = a3;
    __syncthreads();

    const int row = rec[sub];
    if (row >= 0) {
        const float4 p0 = red[0][sub][l];
        const float4 p1 = red[1][sub][l];
        const float4 p2 = red[2][sub][l];
        const float4 p3 = red[3][sub][l];
        const float4 bv = *(const float4*)(bias + (size_t)id * O_ + o0 + 4 * l);
        float4 s;
        s.x = p0.x + p1.x + p2.x + p3.x + bv.x;
        s.y = p0.y + p1.y + p2.y + p3.y + bv.y;
        s.z = p0.z + p1.z + p2.z + p3.z + bv.z;
        s.w = p0.w + p1.w + p2.w + p3.w + bv.w;
        *(float4*)(out + (size_t)row * O_ + o0 + 4 * l) = s;
    }
}

// ---------------------------------------------------------------------- launch
extern "C" void kernel_launch(void* const* d_in, const int* in_sizes, int n_in,
                              void* d_out, int out_size, void* d_ws, size_t ws_size,
                              hipStream_t stream) {
    const int*   x      = (const int*)d_in[0];
    const int*   fact   = (const int*)d_in[1];
    const float* inp    = (const float*)d_in[2];
    const float* params = (const float*)d_in[3];
    const float* bias   = (const float*)d_in[4];
    const int*   msg_to = (const int*)d_in[5];
    const int*   order  = (const int*)d_in[6];
    float*       out    = (float*)d_out;

    const int N = in_sizes[1] / 2;   // 1024
    int* ws = (int*)d_ws;

    hipLaunchKernelGGL(build_quads, dim3(1), dim3(256), 0, stream,
                       x, fact, ws, N);

    // 4x identical gemv launches: timing-decomposition probe.
    // dur = overhead + build + 4*T_gemv  =>  T_gemv = (dur - 51.5us) / 3.
    for (int rep = 0; rep < 4; ++rep) {
        hipLaunchKernelGGL(quad_gemv, dim3(NB), dim3(256), 0, stream,
                           ws, inp, params, bias, msg_to, order, out, N);
    }
}

// Round 12
// 84.751 us; speedup vs baseline: 1.8794x; 1.8794x over previous
//
#include <hip/hip_runtime.h>

#define NATOMS 13
#define NP (NATOMS * NATOMS)   // 169

constexpr int N_ = 1024;   // rows
constexpr int H_ = 512;    // inner dim
constexpr int O_ = 512;    // output dim
constexpr int RB = 4;      // rows per W stream (quad)
constexpr int OSPLIT = 2;
constexpr int OC = O_ / OSPLIT;        // 256 cols per panel (1KB contiguous)
constexpr int MAXQUAD = 384;           // slot space: 8 classes x 48 (>= worst 383)
constexpr int NB = MAXQUAD * OSPLIT;   // 768 blocks
constexpr int RECS = 8;    // ints per quad record: rows[4], id, pad

// ws ints: records at ws+16: slot j has rows[4] at [j*RECS], id at [j*RECS+4]
// (id == -1 -> empty slot). Slot j runs on XCD j%8 (op-major b mapping).
// ----------------------------------------------------------------- build quads
__global__ void build_quads(const int* __restrict__ x,
                            const int* __restrict__ fact,
                            int* __restrict__ ws, int N) {
    __shared__ int s_id[N_];
    __shared__ int s_cnt[NP];
    __shared__ int s_start[NP];
    __shared__ int s_pos[NP];
    __shared__ int s_sorted[N_];
    __shared__ int s_class[NP];    // XCD residue class per group
    __shared__ int s_slot0[NP];    // first slot index (within class) per group
    const int tid = threadIdx.x, bd = blockDim.x;

    for (int i = tid; i < NP; i += bd) { s_cnt[i] = 0; s_pos[i] = 0; }
    __syncthreads();
    for (int n = tid; n < N; n += bd) {
        const int f0 = fact[2 * n];
        const int id = x[f0 * 3 + 1] * NATOMS + x[f0 * 3 + 2];
        s_id[n] = id;
        atomicAdd(&s_cnt[id], 1);
    }
    __syncthreads();
    if (tid == 0) {
        int run = 0;
        int load[8] = {0, 0, 0, 0, 0, 0, 0, 0};
        for (int g = 0; g < NP; ++g) {
            s_start[g] = run;  run += s_cnt[g];
            const int nq = (s_cnt[g] + RB - 1) / RB;
            // greedy: put this group's quads on the least-loaded XCD class
            int xmin = 0;
            for (int k = 1; k < 8; ++k) if (load[k] < load[xmin]) xmin = k;
            s_class[g] = xmin;
            s_slot0[g] = load[xmin];
            load[xmin] += nq;      // max load <= 36avg + 4 < 48  ✓
        }
    }
    __syncthreads();
    // mark all slots empty
    for (int j = tid; j < MAXQUAD; j += bd) ws[16 + j * RECS + RB] = -1;
    for (int n = tid; n < N; n += bd) {
        const int id = s_id[n];
        const int p = atomicAdd(&s_pos[id], 1);
        s_sorted[s_start[id] + p] = n;
    }
    __syncthreads();
    for (int g = tid; g < NP; g += bd) {
        const int c = s_cnt[g], st = s_start[g];
        const int cls = s_class[g], sl0 = s_slot0[g];
        const int nq = (c + RB - 1) / RB;
        for (int k = 0; k < nq; ++k) {
            const int j = cls + 8 * (sl0 + k);   // slot -> XCD j%8 == cls
            int* rec = ws + 16 + (size_t)j * RECS;
            for (int r = 0; r < RB; ++r) {
                const int idx = k * RB + r;
                rec[r] = (idx < c) ? s_sorted[st + idx] : -1;
            }
            rec[RB] = g;
        }
    }
}

// ------------------------------------------------------------------ quad GEMV
// Body identical to R10 (proven). Mapping changed: op-major b -> (quad, op)
// so quad j runs on XCD j%8; build placed same-group quads on one class.
__global__ __launch_bounds__(256)
void quad_gemv(const int* __restrict__ ws,
               const float* __restrict__ inp,
               const float* __restrict__ params,
               const float* __restrict__ bias,
               const int* __restrict__ msg_to_p,
               const int* __restrict__ order_p,
               float* __restrict__ out, int N) {
    const int b = blockIdx.x;
    int quad = b, op = 0;
    if (quad >= MAXQUAD) { quad -= MAXQUAD; op = 1; }

    const int* rec = ws + 16 + (size_t)quad * RECS;
    const int id = rec[RB];
    if (id < 0) return;                // empty slot (evenly spread over XCDs)

    const int msg_to = *msg_to_p;
    const int order  = *order_p;
    const int tid = threadIdx.x;
    const int sub = tid >> 6;        // 0..3: h-phase
    const int l   = tid & 63;        // col-quad within 256-col panel
    const int o0  = op * OC;

    __shared__ float  fp_s[H_][RB];      // 8 KB, [h][r]
    __shared__ float4 red[4][RB][64];    // 16 KB, [sub][r][l]

#pragma unroll
    for (int r = 0; r < RB; ++r) {
        const int row = rec[r];
        if (row >= 0) {
#pragma unroll
            for (int k = 0; k < H_ / 256; ++k) {
                const int h = k * 256 + tid;
                float p = 1.0f;
                for (int i = 0; i < order; ++i)
                    if (i != msg_to)
                        p *= inp[((size_t)i * N + row) * H_ + h];
                fp_s[h][r] = p;
            }
        } else {
#pragma unroll
            for (int k = 0; k < H_ / 256; ++k) fp_s[k * 256 + tid][r] = 0.0f;
        }
    }
    __syncthreads();

    const float* __restrict__ wbase =
        params + (size_t)id * H_ * O_ + (size_t)sub * O_ + o0 + 4 * l;

    float4 a0 = make_float4(0,0,0,0), a1 = a0, a2 = a0, a3 = a0;

#define FMA4(acc, s, wv) acc.x += (s) * wv.x; acc.y += (s) * wv.y;    \
                         acc.z += (s) * wv.z; acc.w += (s) * wv.w;
#pragma unroll 8
    for (int hh = 0; hh < H_ / 4; ++hh) {
        const float4 w = *(const float4*)(wbase + (size_t)hh * 4 * O_);
        const float4 f = *(const float4*)&fp_s[4 * hh + sub][0];
        FMA4(a0, f.x, w)
        FMA4(a1, f.y, w)
        FMA4(a2, f.z, w)
        FMA4(a3, f.w, w)
    }
#undef FMA4

    red[sub][0][l] = a0;
    red[sub][1][l] = a1;
    red[sub][2][l] = a2;
    red[sub][3][l] = a3;
    __syncthreads();

    const int row = rec[sub];
    if (row >= 0) {
        const float4 p0 = red[0][sub][l];
        const float4 p1 = red[1][sub][l];
        const float4 p2 = red[2][sub][l];
        const float4 p3 = red[3][sub][l];
        const float4 bv = *(const float4*)(bias + (size_t)id * O_ + o0 + 4 * l);
        float4 s;
        s.x = p0.x + p1.x + p2.x + p3.x + bv.x;
        s.y = p0.y + p1.y + p2.y + p3.y + bv.y;
        s.z = p0.z + p1.z + p2.z + p3.z + bv.z;
        s.w = p0.w + p1.w + p2.w + p3.w + bv.w;
        *(float4*)(out + (size_t)row * O_ + o0 + 4 * l) = s;
    }
}

// ---------------------------------------------------------------------- launch
extern "C" void kernel_launch(void* const* d_in, const int* in_sizes, int n_in,
                              void* d_out, int out_size, void* d_ws, size_t ws_size,
                              hipStream_t stream) {
    const int*   x      = (const int*)d_in[0];
    const int*   fact   = (const int*)d_in[1];
    const float* inp    = (const float*)d_in[2];
    const float* params = (const float*)d_in[3];
    const float* bias   = (const float*)d_in[4];
    const int*   msg_to = (const int*)d_in[5];
    const int*   order  = (const int*)d_in[6];
    float*       out    = (float*)d_out;

    const int N = in_sizes[1] / 2;   // 1024
    int* ws = (int*)d_ws;

    hipLaunchKernelGGL(build_quads, dim3(1), dim3(256), 0, stream,
                       x, fact, ws, N);

    hipLaunchKernelGGL(quad_gemv, dim3(NB), dim3(256), 0, stream,
                       ws, inp, params, bias, msg_to, order, out, N);
}